// Round 1
// baseline (97.955 us; speedup 1.0000x reference)
//
#include <hip/hip_runtime.h>

// Problem constants
#define BATCH 8
#define HW_N  1024   // 32*32
#define CD    128    // channels
#define W_IMG 32
#define CH_O  30
#define F_N   900    // 30*30

// Workspace layout (bytes)
#define OFF_Q16 0u          // 8192*128*2 = 2 MB
#define OFF_K16 2097152u
#define OFF_V   4194304u    // 32 KB
#define OFF_D   4227072u    // 8192*25*4 = 819200
#define OFF_TP  5046272u    // 8192*8 doubles
#define OFF_TVP 5570560u    // -> 6094848

typedef _Float16 f16x8 __attribute__((ext_vector_type(8)));
typedef _Float16 f16x4 __attribute__((ext_vector_type(4)));
typedef float    f32x4 __attribute__((ext_vector_type(4)));

// MFMA-fragment-order layout for row-major [R][k]:
// off(R,k) = (R>>4)*2048 + [ (k>>5)*4 + ((k>>3)&3) ]*128 + (R&15)*8 + (k&7)
__device__ __forceinline__ void async16(const void* g, void* l) {
    __builtin_amdgcn_global_load_lds(
        (const __attribute__((address_space(1))) unsigned int*)g,
        (__attribute__((address_space(3))) unsigned int*)l,
        16, 0, 0);
}

__device__ __forceinline__ f16x8 cvt8(const float* __restrict__ p) {
    float4 a = *(const float4*)p;
    float4 b = *(const float4*)(p + 4);
    f16x8 h;
    h[0] = (_Float16)a.x; h[1] = (_Float16)a.y;
    h[2] = (_Float16)a.z; h[3] = (_Float16)a.w;
    h[4] = (_Float16)b.x; h[5] = (_Float16)b.y;
    h[6] = (_Float16)b.z; h[7] = (_Float16)b.w;
    return h;
}

// -------------------------------------------------------------------------
// Kernel A: Q/K via fp16 MFMA, weights converted in-register from fp32
// (prep kernel folded in); V fp32. 512 blocks x 16 rows.
// Q16/K16 written via LDS bounce -> fully coalesced 16B stores.
// -------------------------------------------------------------------------
__global__ __launch_bounds__(256) void qkv_kernel(
    const float* __restrict__ xf,
    const float* __restrict__ Wq, const float* __restrict__ Wk,
    const float* __restrict__ bq, const float* __restrict__ bk,
    const float* __restrict__ wv, const float* __restrict__ bv,
    _Float16* __restrict__ Q16, _Float16* __restrict__ K16,
    float* __restrict__ V)
{
    __shared__ float    xs[16][132];
    __shared__ _Float16 xh[2048];
    __shared__ _Float16 qtile[2048];
    __shared__ _Float16 ktile[2048];

    const int t = threadIdx.x;
    const int rowbase = blockIdx.x * 16;
    const int w    = t >> 6;
    const int lane = t & 63;
    const int q    = lane >> 4;
    const int i    = lane & 15;

    // B-frags straight from fp32 weights (L2-hot, 32B/lane):
    // lane (q,i), ct, ks needs W[c=(w*2+ct)*16+i][k = ks*32+q*8 .. +7]
    f16x8 wqf[2][4], wkf[2][4];
#pragma unroll
    for (int ct = 0; ct < 2; ++ct) {
        const size_t c = (size_t)((w * 2 + ct) * 16 + i);
#pragma unroll
        for (int ks = 0; ks < 4; ++ks) {
            wqf[ct][ks] = cvt8(&Wq[c * CD + ks * 32 + q * 8]);
            wkf[ct][ks] = cvt8(&Wk[c * CD + ks * 32 + q * 8]);
        }
    }

    // stage 16x128 fp32 rows (for V) + fp16 copy in A-frag order (for MFMA)
#pragma unroll
    for (int m = 0; m < 2; ++m) {
        int id = t + 256 * m;          // 0..511 float4 chunks
        int r  = id >> 5;
        int c4 = id & 31;
        float4 v4 = *(const float4*)&xf[(size_t)(rowbase + r) * CD + c4 * 4];
        *(float4*)&xs[r][c4 * 4] = v4;
        int c = c4 * 4;
        int off = ((c >> 5) * 4 + ((c >> 3) & 3)) * 128 + r * 8 + (c & 7);
        f16x4 hh;
        hh[0] = (_Float16)v4.x; hh[1] = (_Float16)v4.y;
        hh[2] = (_Float16)v4.z; hh[3] = (_Float16)v4.w;
        *(f16x4*)&xh[off] = hh;
    }
    __syncthreads();

    f32x4 aq[2], ak[2];
#pragma unroll
    for (int ct = 0; ct < 2; ++ct) {
        aq[ct] = (f32x4){0.f, 0.f, 0.f, 0.f};
        ak[ct] = (f32x4){0.f, 0.f, 0.f, 0.f};
    }

#pragma unroll
    for (int ks = 0; ks < 4; ++ks) {
        const int aoff = (ks * 4 + q) * 128 + i * 8;
        f16x8 ah = *(f16x8*)&xh[aoff];
#pragma unroll
        for (int ct = 0; ct < 2; ++ct) {
            aq[ct] = __builtin_amdgcn_mfma_f32_16x16x32_f16(ah, wqf[ct][ks], aq[ct], 0, 0, 0);
            ak[ct] = __builtin_amdgcn_mfma_f32_16x16x32_f16(ah, wkf[ct][ks], ak[ct], 0, 0, 0);
        }
    }

    // epilogue: bias, frag-order LDS bounce, then coalesced 16B stores
#pragma unroll
    for (int ct = 0; ct < 2; ++ct) {
        int c = (w * 2 + ct) * 16 + i;
        float bqv = bq[c], bkv = bk[c];
        int coff = ((c >> 5) * 4 + ((c >> 3) & 3)) * 128 + (c & 7);
#pragma unroll
        for (int g = 0; g < 4; ++g) {
            int off = coff + (q * 4 + g) * 8;
            qtile[off] = (_Float16)(aq[ct][g] + bqv);
            ktile[off] = (_Float16)(ak[ct][g] + bkv);
        }
    }
    __syncthreads();

    {   // Q16/K16 tile for this block is contiguous: base = rowbase*128 f16
        f16x8 qv = *(f16x8*)&qtile[t * 8];
        f16x8 kv = *(f16x8*)&ktile[t * 8];
        *(f16x8*)&Q16[(size_t)rowbase * 128 + t * 8] = qv;
        *(f16x8*)&K16[(size_t)rowbase * 128 + t * 8] = kv;
    }

    // V: wave-parallel row dot (8 lanes per row)
    if (t < 128) {
        int r = t >> 3, l = t & 7;
        float s = 0.f;
#pragma unroll
        for (int k = 0; k < 16; ++k) {
            int c = l + k * 8;
            s += xs[r][c] * wv[c];
        }
        s += __shfl_xor(s, 1);
        s += __shfl_xor(s, 2);
        s += __shfl_xor(s, 4);
        if (l == 0) V[rowbase + r] = s + bv[0];
    }
}

// -------------------------------------------------------------------------
// Kernel B: S = Q@K^T; fused exp/rowsums/band. Single-stage 64KB staging
// (one vmcnt(0)+barrier instead of two). grid (8,8,8); 256 thr = 4 waves.
// -------------------------------------------------------------------------
#define A_OFF 0
#define B_OFF 32768
#define SCR2 16896
#define ATTN_LDS_TOTAL 65536

__global__ __launch_bounds__(256) void attn_kernel(
    const _Float16* __restrict__ Q16, const _Float16* __restrict__ K16,
    const float* __restrict__ V,
    double* __restrict__ Tp, double* __restrict__ TVp,
    float* __restrict__ D)
{
    extern __shared__ char lds[];
    _Float16* Ah = (_Float16*)(lds + A_OFF);
    _Float16* Bh = (_Float16*)(lds + B_OFF);
    __shared__ float Vs[128];

    const int b  = blockIdx.x;
    const int rb = blockIdx.y;
    const int cb = blockIdx.z;
    const int t  = threadIdx.x;
    const int w    = t >> 6;
    const int lane = t & 63;
    const int q    = lane >> 4;
    const int i    = lane & 15;
    const int wy = w >> 1, wx = w & 1;

    if (t < 128) Vs[t] = V[b * HW_N + cb * 128 + t];

    const size_t abase = (size_t)(b * 8 + rb) * 16384;   // fp16 units
    const size_t bbase = (size_t)(b * 8 + cb) * 16384;

    // single-shot staging: full 128x128 tiles, identity layout (frag order)
#pragma unroll
    for (int m = 0; m < 8; ++m) {
        int id = t + 256 * m;                    // 0..2047, 16B chunks
        async16(Q16 + abase + (size_t)id * 8, Ah + id * 8);
        async16(K16 + bbase + (size_t)id * 8, Bh + id * 8);
    }
    asm volatile("s_waitcnt vmcnt(0)" ::: "memory");
    __syncthreads();

    f32x4 acc[4][4];
#pragma unroll
    for (int r = 0; r < 4; ++r)
#pragma unroll
        for (int f = 0; f < 4; ++f) acc[r][f] = (f32x4){0.f, 0.f, 0.f, 0.f};

#pragma unroll
    for (int kcl = 0; kcl < 4; ++kcl) {
        f16x8 a4[4], b4[4];
#pragma unroll
        for (int r = 0; r < 4; ++r) {
            int ao = (wy * 4 + r) * 2048 + (kcl * 4 + q) * 128 + i * 8;
            a4[r] = *(f16x8*)&Ah[ao];
            int bo = (wx * 4 + r) * 2048 + (kcl * 4 + q) * 128 + i * 8;
            b4[r] = *(f16x8*)&Bh[bo];
        }
#pragma unroll
        for (int r = 0; r < 4; ++r)
#pragma unroll
            for (int f = 0; f < 4; ++f)
                acc[r][f] = __builtin_amdgcn_mfma_f32_16x16x32_f16(
                    a4[r], b4[f], acc[r][f], 0, 0, 0);
    }

    // ---- epilogue: exp, partial row sums, banded D store ----
    float st[4][4], stv[4][4];
#pragma unroll
    for (int r = 0; r < 4; ++r)
#pragma unroll
        for (int g = 0; g < 4; ++g) { st[r][g] = 0.f; stv[r][g] = 0.f; }

    const bool band = (cb - rb <= 1) && (rb - cb <= 1);

#pragma unroll
    for (int f = 0; f < 4; ++f) {
        int col_local = wx * 64 + f * 16 + i;
        int hw_c = cb * 128 + col_local;
        float v = Vs[col_local];
        int cimg_r = hw_c >> 5, cimg_c = hw_c & 31;
#pragma unroll
        for (int r = 0; r < 4; ++r)
#pragma unroll
            for (int g = 0; g < 4; ++g) {
                float e = __expf(acc[r][f][g]);
                st[r][g]  += e;
                stv[r][g] += e * v;
                if (band) {
                    int row_local = wy * 64 + r * 16 + q * 4 + g;
                    int hw_r = rb * 128 + row_local;
                    int dy = cimg_r - (hw_r >> 5);
                    int dx = cimg_c - (hw_r & 31);
                    if ((unsigned)(dy + 2) <= 4u && (unsigned)(dx + 2) <= 4u)
                        D[(size_t)(b * HW_N + hw_r) * 25 + (dy + 2) * 5 + (dx + 2)] = e;
                }
            }
    }

    // ---- block reduction (scratch aliases staging LDS) -> double partials ----
    __syncthreads();
    float* scrT  = (float*)lds;              // 128 x 33 fp32
    float* scrTV = (float*)(lds + SCR2);
#pragma unroll
    for (int r = 0; r < 4; ++r)
#pragma unroll
        for (int g = 0; g < 4; ++g) {
            int rl = wy * 64 + r * 16 + q * 4 + g;
            scrT [rl * 33 + wx * 16 + i] = st[r][g];
            scrTV[rl * 33 + wx * 16 + i] = stv[r][g];
        }
    __syncthreads();
    if (t < 128) {
        double s = 0.0;
#pragma unroll
        for (int c = 0; c < 32; ++c) s += (double)scrT[t * 33 + c];
        Tp[(size_t)(b * HW_N + rb * 128 + t) * 8 + cb] = s;
    } else {
        int tt = t - 128;
        double s = 0.0;
#pragma unroll
        for (int c = 0; c < 32; ++c) s += (double)scrTV[tt * 33 + c];
        TVp[(size_t)(b * HW_N + rb * 128 + tt) * 8 + cb] = s;
    }
}

// -------------------------------------------------------------------------
// Kernel C: sum partials -> T,TV; gates; out = sum_p gate_p * xf rows.
// grid (30, 8, 2): z = channel half -> 480 blocks, halved staging latency.
// -------------------------------------------------------------------------
__global__ __launch_bounds__(256) void gate_out_kernel(
    const float* __restrict__ xf, const float* __restrict__ V,
    const double* __restrict__ Tp, const double* __restrict__ TVp,
    const float* __restrict__ D, float* __restrict__ out)
{
    const int fi = blockIdx.x;   // 0..29
    const int b  = blockIdx.y;
    const int zh = blockIdx.z;   // channel half 0/1
    const int t  = threadIdx.x;

    __shared__ float  xs[96 * 68];    // 3 img rows x 32 cols x 64 ch (+4 pad)
    __shared__ float  gates[32][9];
    __shared__ double Ts[96], TVs[96];

#pragma unroll
    for (int m = 0; m < 6; ++m) {
        int id   = t + 256 * m;       // 0..1535, 16B chunks
        int srow = id >> 4;
        int c4   = id & 15;
        int r3   = srow >> 5, colc = srow & 31;
        *(float4*)&xs[srow * 68 + c4 * 4] =
            *(const float4*)&xf[((size_t)(b * 32 + fi + r3) * 32 + colc) * CD + zh * 64 + c4 * 4];
    }

    if (t < 96) {
        int R = b * HW_N + (fi + (t >> 5)) * W_IMG + (t & 31);
        double s = 0.0;
#pragma unroll
        for (int c = 0; c < 8; ++c) s += Tp[(size_t)R * 8 + c];
        Ts[t] = s;
    } else if (t >= 128 && t < 224) {
        int tt = t - 128;
        int R = b * HW_N + (fi + (tt >> 5)) * W_IMG + (tt & 31);
        double s = 0.0;
#pragma unroll
        for (int c = 0; c < 8; ++c) s += TVp[(size_t)R * 8 + c];
        TVs[tt] = s;
    }
    __syncthreads();

    for (int g = t; g < 270; g += 256) {
        int fj = g / 9, p = g % 9;
        int pr = p / 3, pc = p % 3;
        int lrow = pr * 32 + fj + pc;
        int ip = (fi + pr) * W_IMG + (fj + pc);
        const float* Drow = &D[(size_t)(b * HW_N + ip) * 25];
        double se = 0.0, sev = 0.0;
#pragma unroll
        for (int qq = 0; qq < 9; ++qq) {
            int qr = qq / 3, qc = qq % 3;
            float e = Drow[(qr - pr + 2) * 5 + (qc - pc + 2)];
            se  += (double)e;
            sev += (double)(e * V[b * HW_N + (fi + qr) * W_IMG + (fj + qc)]);
        }
        double denom = Ts[lrow] - se + 1e-5;
        double numer = TVs[lrow] - sev;
        gates[fj][p] = (float)(numer / denom);
    }
    __syncthreads();

    // vectorized epilogue: thread = (c4 channel-quad of this half, fj lane)
    const int c4  = t & 15;      // 16 quads = 64 channels
    const int fjl = t >> 4;      // 0..15
#pragma unroll
    for (int it = 0; it < 2; ++it) {
        int fj = fjl + 16 * it;  // 0..31
        if (fj < CH_O) {
            f32x4 o = (f32x4){0.f, 0.f, 0.f, 0.f};
#pragma unroll
            for (int p = 0; p < 9; ++p) {
                int pr = p / 3, pc = p % 3;
                f32x4 x = *(f32x4*)&xs[(pr * 32 + fj + pc) * 68 + c4 * 4];
                float gv = gates[fj][p];
                o += gv * x;
            }
            *(f32x4*)&out[((size_t)(b * F_N) + fi * CH_O + fj) * CD + zh * 64 + c4 * 4] = o;
        }
    }
}

// -------------------------------------------------------------------------
extern "C" void kernel_launch(void* const* d_in, const int* in_sizes, int n_in,
                              void* d_out, int out_size, void* d_ws, size_t ws_size,
                              hipStream_t stream)
{
    (void)in_sizes; (void)n_in; (void)out_size; (void)ws_size;
    const float* batch = (const float*)d_in[0];
    const float* Wq    = (const float*)d_in[1];
    const float* bq    = (const float*)d_in[2];
    const float* Wk    = (const float*)d_in[3];
    const float* bk    = (const float*)d_in[4];
    const float* wv    = (const float*)d_in[5];
    const float* bv    = (const float*)d_in[6];

    char*      ws  = (char*)d_ws;
    _Float16*  Q16 = (_Float16*)(ws + OFF_Q16);
    _Float16*  K16 = (_Float16*)(ws + OFF_K16);
    float*     V   = (float*)(ws + OFF_V);
    float*     D   = (float*)(ws + OFF_D);
    double*    Tp  = (double*)(ws + OFF_TP);
    double*    TVp = (double*)(ws + OFF_TVP);
    float*     out = (float*)d_out;

    qkv_kernel<<<dim3(512), dim3(256), 0, stream>>>(batch, Wq, Wk, bq, bk, wv, bv,
                                                    Q16, K16, V);
    attn_kernel<<<dim3(8, 8, 8), dim3(256), ATTN_LDS_TOTAL, stream>>>(
        Q16, K16, V, Tp, TVp, D);
    gate_out_kernel<<<dim3(CH_O, BATCH, 2), dim3(256), 0, stream>>>(batch, V, Tp, TVp, D, out);
}